// Round 1
// 82.288 us; speedup vs baseline: 1.1477x; 1.1477x over previous
//
#include <hip/hip_runtime.h>

#define HALF   4096
#define NROWS  8192
#define DDIM   128
#define NGROUPS (NROWS / 128)                  // 64 row/col groups of 128
#define NPAIRS  (NGROUPS * (NGROUPS + 1) / 2)  // 2080 triangular tile-blocks
#define LDS_STRIDE 272                          // 256B row + 16B pad (conflict-free b128)

typedef _Float16 v8h __attribute__((ext_vector_type(8)));
typedef _Float16 v2h __attribute__((ext_vector_type(2)));
typedef float    v4f __attribute__((ext_vector_type(4)));

#if __has_builtin(__builtin_amdgcn_exp2f)
#define EXP2F(x) __builtin_amdgcn_exp2f(x)
#else
#define EXP2F(x) exp2f(x)
#endif
#if __has_builtin(__builtin_amdgcn_logf)
#define LOG2F(x) __builtin_amdgcn_logf(x)
#else
#define LOG2F(x) __log2f(x)
#endif

#define CEXP 2.8853900817779268f   // 2/ln2 : exp(2g-2) = 2^(CEXP*g - CEXP)

// ---------------- Kernel 1: row-normalize concat(z_i, z_j) -> fp16; zero S ----
__global__ __launch_bounds__(256) void nt_normalize(
        const float* __restrict__ z_i, const float* __restrict__ z_j,
        _Float16* __restrict__ zn, float* __restrict__ S) {
    int tid  = threadIdx.x;
    int lane = tid & 63;
    int row  = blockIdx.x * 4 + (tid >> 6);
    // zero the S accumulators nt_gram_sym atomicAdds into (ws is 0xAA-poisoned).
    // P needs no zero: every entry is plain-stored exactly once by gram.
    if (tid < 4) S[blockIdx.x * 4 + tid] = 0.f;

    const float* src = (row < HALF) ? (z_i + (size_t)row * DDIM)
                                    : (z_j + (size_t)(row - HALF) * DDIM);
    float2 v = *(const float2*)(src + lane * 2);
    float ss = v.x * v.x + v.y * v.y;
    #pragma unroll
    for (int off = 32; off >= 1; off >>= 1)
        ss += __shfl_xor(ss, off, 64);
    float inv = 1.0f / fmaxf(sqrtf(ss), 1e-8f);
    v2h p;
    p.x = (_Float16)(v.x * inv);
    p.y = (_Float16)(v.y * inv);
    *(v2h*)(zn + (size_t)row * DDIM + lane * 2) = p;
}

// ---------------- Kernel 2: symmetric Gram + shifted sum-exp, triangular tiles ----
// 2080 blocks = upper-triangle (I<=J) of the 64x64 grid of 128x128 tiles.
// R3-proven shape: 4 waves each own 32 rows (a[2][4] = 32 VGPRs of A-frags,
// 2 live accumulators) x all 128 cols; 8 column-subtiles.
// exp(sim) is symmetric: off-diagonal tiles scatter row-sums AND column-sums.
// New this round:
//  (a) column-sum partials are combined across the 4 waves in LDS first ->
//      128 atomics/block instead of 512 (4x less same-line atomic pressure);
//  (b) partner tiles (J == I+32) hold sim(r, r+HALF) on their local diagonal:
//      the already-computed exp value is stored to P[r] with a predicated
//      store, so the old nt_correct dot-product recompute (2 MB zn re-read +
//      16 serial shfl-tree iterations per wave) is deleted entirely.
__global__ __launch_bounds__(256, 4) void nt_gram_sym(
        const _Float16* __restrict__ zn, float* __restrict__ S,
        float* __restrict__ P) {
    __shared__ unsigned char lds[128 * LDS_STRIDE];   // 34816 B
    __shared__ float cs[4][128];                      // +2048 B (col-sum combine)

    int tid  = threadIdx.x;
    int lane = tid & 63;
    int w    = tid >> 6;       // wave 0..3
    int quad = lane >> 4;      // 0..3
    int cl   = lane & 15;      // 0..15

    // decode triangular pair index -> (I, J), I <= J
    int p = blockIdx.x;
    int J = (int)((sqrtf(8.0f * (float)p + 1.0f) - 1.0f) * 0.5f);
    while ((J + 1) * (J + 2) / 2 <= p) ++J;
    while (J * (J + 1) / 2 > p) --J;
    int I = p - J * (J + 1) / 2;
    int r0 = I * 128, c0 = J * 128;
    bool offdiag = (I != J);
    bool ppart   = (J == I + 32);   // this tile's local diagonal = partner sims

    // A fragments: wave w owns 32 rows (2 tiles of 16), kept in registers.
    // A-operand layout: lane holds A[m = lane&15][k = quad*8 + j]
    v8h a[2][4];
    #pragma unroll
    for (int u = 0; u < 2; ++u) {
        int arow = r0 + w * 32 + u * 16 + cl;
        #pragma unroll
        for (int t = 0; t < 4; ++t)
            a[u][t] = *(const v8h*)(zn + (size_t)arow * DDIM + t * 32 + quad * 8);
    }

    // stage the 128-column tile (128 x 128 f16 = 32 KB) once, padded rows
    const uint4* gb = (const uint4*)zn;   // 1 uint4 = 8 f16
    #pragma unroll
    for (int i = 0; i < 8; ++i) {
        int rr = (tid >> 4) + i * 16;     // column index within tile
        uint4 v = gb[(size_t)(c0 + rr) * 16 + (tid & 15)];
        *(uint4*)&lds[(size_t)rr * LDS_STRIDE + (tid & 15) * 16] = v;
    }
    __syncthreads();

    float sums[2][4] = {{0.f,0.f,0.f,0.f},{0.f,0.f,0.f,0.f}};

    #pragma unroll
    for (int sub = 0; sub < 8; ++sub) {
        v4f acc0 = {0.f, 0.f, 0.f, 0.f};
        v4f acc1 = {0.f, 0.f, 0.f, 0.f};
        #pragma unroll
        for (int t = 0; t < 4; ++t) {
            v8h b = *(const v8h*)&lds[(size_t)(sub * 16 + cl) * LDS_STRIDE + t * 64 + quad * 16];
            acc0 = __builtin_amdgcn_mfma_f32_16x16x32_f16(a[0][t], b, acc0, 0, 0, 0);
            acc1 = __builtin_amdgcn_mfma_f32_16x16x32_f16(a[1][t], b, acc1, 0, 0, 0);
        }
        // epilogue: exp(2g-2); row sums in regs, column sums cross-lane.
        // C/D layout (16x16x32): col = lane&15, row = quad*4 + r.
        float cp = 0.f;
        #pragma unroll
        for (int r = 0; r < 4; ++r) {
            float e0 = EXP2F(fmaf(acc0[r], CEXP, -CEXP));
            float e1 = EXP2F(fmaf(acc1[r], CEXP, -CEXP));
            sums[0][r] += e0;
            sums[1][r] += e1;
            cp += e0 + e1;
            // partner-pair harvest: local row == local col  <=>
            // sub == w*2 + u  &&  cl == quad*4 + r  (sub is unrolled-constant)
            if (ppart && cl == quad * 4 + r) {
                if (sub == w * 2)     P[r0 + w * 32 +      quad * 4 + r] = e0;
                if (sub == w * 2 + 1) P[r0 + w * 32 + 16 + quad * 4 + r] = e1;
            }
        }
        if (offdiag) {
            // column partials: reduce over the wave's 32 rows (across quads),
            // park in LDS — cross-wave combine after the loop (1 atomic/col).
            cp += __shfl_xor(cp, 16, 64);
            cp += __shfl_xor(cp, 32, 64);
            if (quad == 0)
                cs[w][sub * 16 + cl] = cp;
        }
    }

    // row sums: reduce across the 16 column-lanes, one atomic per row
    #pragma unroll
    for (int u = 0; u < 2; ++u)
        #pragma unroll
        for (int r = 0; r < 4; ++r) {
            float s = sums[u][r];
            #pragma unroll
            for (int off = 1; off < 16; off <<= 1)
                s += __shfl_xor(s, off, 64);
            if (cl == 0)
                atomicAdd(&S[r0 + w * 32 + u * 16 + quad * 4 + r], s);
        }

    // column sums: combine the 4 waves' partials, one atomic per column
    if (offdiag) {                 // block-uniform -> barrier is safe
        __syncthreads();
        if (tid < 128) {
            float c = cs[0][tid] + cs[1][tid] + cs[2][tid] + cs[3][tid];
            atomicAdd(&S[c0 + tid], c);
        }
    }
}

// ---------------- Kernel 3: log(S - e_partner), reduce, scale — ONE block ----
// Replaces the old nt_correct (64 blocks x 16 serial dot products re-reading
// 2 MB of zn) + nt_final (1-thread launch). e_partner comes precomputed from
// the gram kernel's partner tiles via P. 4096 pairs / 1024 threads = 4 each:
// 12 coalesced loads + 8 log2 per thread, wave shfl-reduce, LDS combine,
// single store. No acc buffer, no global atomics, one fewer dispatch.
__global__ __launch_bounds__(1024) void nt_correct(
        const float* __restrict__ S, const float* __restrict__ P,
        float* __restrict__ out) {
    int tid = threadIdx.x;
    float part = 0.f;
    #pragma unroll
    for (int k = 0; k < 4; ++k) {
        int pr = tid + k * 1024;
        float e = P[pr];
        part += LOG2F(S[pr] - e) + LOG2F(S[pr + HALF] - e);
    }
    #pragma unroll
    for (int off = 32; off >= 1; off >>= 1)
        part += __shfl_xor(part, off, 64);
    __shared__ float red[16];
    if ((tid & 63) == 0) red[tid >> 6] = part;
    __syncthreads();
    if (tid == 0) {
        float t = 0.f;
        #pragma unroll
        for (int i = 0; i < 16; ++i) t += red[i];
        out[0] = t * (0.69314718055994531f / (float)NROWS);
    }
}

extern "C" void kernel_launch(void* const* d_in, const int* in_sizes, int n_in,
                              void* d_out, int out_size, void* d_ws, size_t ws_size,
                              hipStream_t stream) {
    const float* z_i = (const float*)d_in[0];
    const float* z_j = (const float*)d_in[1];
    _Float16* zn  = (_Float16*)d_ws;                                    // 2 MB
    float*    S   = (float*)((char*)d_ws + (size_t)NROWS * DDIM * 2);   // 8192 f32
    float*    P   = S + NROWS;                                          // 4096 f32
    float*    out = (float*)d_out;

    nt_normalize<<<dim3(NROWS / 4), dim3(256), 0, stream>>>(z_i, z_j, zn, S);
    nt_gram_sym<<<dim3(NPAIRS), dim3(256), 0, stream>>>(zn, S, P);
    nt_correct<<<dim3(1), dim3(1024), 0, stream>>>(S, P, out);
}